// Round 3
// baseline (373.608 us; speedup 1.0000x reference)
//
#include <hip/hip_runtime.h>
#include <math.h>

// EnhancedTripletLoss, B=8192, D=256, 8 classes.
// R3: single-plane bf16 mining, fragment-major pre-layout, direct
// global->register MFMA (no LDS, no barriers in the hot loop).
// Selection on v = sq_j - 2*dot (monotone per anchor); exact fp32 recompute
// of the mined triplet distances (matches F.pairwise_distance eps semantics).

typedef __attribute__((ext_vector_type(8))) short short8;
typedef __attribute__((ext_vector_type(4))) float floatx4;

#define B_N 8192
#define D_K 256
#define NJ  8     // j-chunks (grid.y); partial slots = NJ*2 (one per wj half)
#define NP  16

__device__ __forceinline__ unsigned short f2bf_rne(float f) {
  unsigned u = __float_as_uint(f);
  u += 0x7FFFu + ((u >> 16) & 1u);
  return (unsigned short)(u >> 16);
}

// ---- split to bf16 in MFMA-fragment-major layout + row norms + zero accums ----
// xhf layout: tile (16 rows x 32 k) = 1KB, frag-ordered: elem(lane,j) at
// [tile_row][tk][lane*8 + j], lane = quad*16 + m, row = 16*tile_row + m,
// k = 32*tk + quad*8 + j.  tile stride over tk is inner -> sequential k-loop.
__global__ void k_split(const float* __restrict__ x, unsigned short* __restrict__ xhf,
                        float* __restrict__ sq, float* __restrict__ sum,
                        int* __restrict__ cnt, int* __restrict__ done) {
  __shared__ float sw[64];
  const int tid  = threadIdx.x;
  const int lane = tid & 63;
  const int w    = tid >> 6;
  const int b    = blockIdx.x;        // tile_row
  const int m    = lane & 15;
  const int quad = lane >> 4;
  const int row  = b * 16 + m;

  float s = 0.f;
#pragma unroll
  for (int h = 0; h < 2; ++h) {
    int tk = w + h * 4;
    int kk = tk * 32 + quad * 8;
    float4 f0 = *reinterpret_cast<const float4*>(x + (size_t)row * D_K + kk);
    float4 f1 = *reinterpret_cast<const float4*>(x + (size_t)row * D_K + kk + 4);
    s += f0.x * f0.x + f0.y * f0.y + f0.z * f0.z + f0.w * f0.w;
    s += f1.x * f1.x + f1.y * f1.y + f1.z * f1.z + f1.w * f1.w;
    ushort4 lo, hi;
    lo.x = f2bf_rne(f0.x); lo.y = f2bf_rne(f0.y); lo.z = f2bf_rne(f0.z); lo.w = f2bf_rne(f0.w);
    hi.x = f2bf_rne(f1.x); hi.y = f2bf_rne(f1.y); hi.z = f2bf_rne(f1.z); hi.w = f2bf_rne(f1.w);
    size_t o = ((size_t)b * 8 + tk) * 512 + lane * 8;
    *reinterpret_cast<ushort4*>(xhf + o)     = lo;
    *reinterpret_cast<ushort4*>(xhf + o + 4) = hi;
  }
  // reduce s over the 4 quads that share row m
  s += __shfl_xor(s, 16);
  s += __shfl_xor(s, 32);
  if (quad == 0) sw[w * 16 + m] = s;
  __syncthreads();
  if (tid < 16) sq[b * 16 + tid] = sw[tid] + sw[16 + tid] + sw[32 + tid] + sw[48 + tid];
  if (b == 0 && tid == 0) { *sum = 0.f; *cnt = 0; *done = 0; }
}

// ---- MFMA Gram + hard mining, no LDS ----
// Block: 128 anchors x 1024 candidates (8 subtiles of 128). 4 waves 2x2,
// wave tile 64x64 = 4x4 MFMA 16x16x32 tiles. Frags loaded straight from the
// fragment-major xhf: one coalesced b128 per tile per k-step.
__global__ __launch_bounds__(256, 2) void k_mine3(
    const unsigned short* __restrict__ xhf, const int* __restrict__ lab,
    const float* __restrict__ sq,
    float* __restrict__ pv, int* __restrict__ pi,
    float* __restrict__ nv, int* __restrict__ ni) {
  const int tid  = threadIdx.x;
  const int lane = tid & 63;
  const int w    = tid >> 6;
  const int wi   = w >> 1, wj = w & 1;
  const int quad = lane >> 4, l15 = lane & 15;
  const int i0   = blockIdx.x * 128;
  const int jblk = blockIdx.y * (B_N / NJ);

  // A frag base: tile_rows (i0/16 + wi*4 + mt), tk-major inside (stride 512 shorts)
  const unsigned short* Ab = xhf + ((size_t)(blockIdx.x * 8 + wi * 4) * 8) * 512 + lane * 8;
  const unsigned short* Bb0 = xhf + ((size_t)(blockIdx.y * (B_N / NJ / 16) + wj * 4) * 8) * 512 + lane * 8;

  float bpv[16], bnv[16];
  int   bpi[16], bni[16];
  unsigned lip0 = 0, lip1 = 0;
#pragma unroll
  for (int r = 0; r < 16; ++r) {
    bpv[r] = -1e30f; bnv[r] = 1e30f; bpi[r] = -1; bni[r] = -1;
    int ir = i0 + wi * 64 + (r >> 2) * 16 + quad * 4 + (r & 3);
    unsigned lv = (unsigned)lab[ir] & 0xFu;
    if (r < 8) lip0 |= lv << (r * 4); else lip1 |= lv << ((r - 8) * 4);
  }

  short8 ca[4], cb[4];
#pragma unroll
  for (int mt = 0; mt < 4; ++mt) ca[mt] = *(const short8*)(Ab + (size_t)mt * 8 * 512);
#pragma unroll
  for (int nt = 0; nt < 4; ++nt) cb[nt] = *(const short8*)(Bb0 + (size_t)nt * 8 * 512);

  for (int sub = 0; sub < 8; ++sub) {
    floatx4 acc[16];
#pragma unroll
    for (int q = 0; q < 16; ++q) acc[q] = (floatx4)0.f;

#pragma unroll
    for (int tk = 0; tk < 8; ++tk) {
      short8 na[4], nb[4];
      int t = sub * 8 + tk + 1;
      if (t < 64) {           // prefetch next k-step (possibly next subtile)
        int nsub = t >> 3, ntk = t & 7;
        const unsigned short* An = Ab + (size_t)ntk * 512;
        const unsigned short* Bn = xhf +
            ((size_t)(blockIdx.y * (B_N / NJ / 16) + nsub * 8 + wj * 4) * 8 + ntk) * 512 + lane * 8;
#pragma unroll
        for (int mt = 0; mt < 4; ++mt) na[mt] = *(const short8*)(An + (size_t)mt * 8 * 512);
#pragma unroll
        for (int nt = 0; nt < 4; ++nt) nb[nt] = *(const short8*)(Bn + (size_t)nt * 8 * 512);
      }
#pragma unroll
      for (int mt = 0; mt < 4; ++mt)
#pragma unroll
        for (int nt = 0; nt < 4; ++nt)
          acc[mt * 4 + nt] = __builtin_amdgcn_mfma_f32_16x16x32_bf16(ca[mt], cb[nt], acc[mt * 4 + nt], 0, 0, 0);
#pragma unroll
      for (int q = 0; q < 4; ++q) { ca[q] = na[q]; cb[q] = nb[q]; }
    }

    // selection on v = sq_j - 2*dot
    const int j0 = jblk + sub * 128;
#pragma unroll
    for (int nt = 0; nt < 4; ++nt) {
      int   j  = j0 + wj * 64 + nt * 16 + l15;
      int   jl = lab[j];
      float sj = sq[j];
#pragma unroll
      for (int r = 0; r < 16; ++r) {
        int mt = r >> 2, reg = r & 3;
        float v  = fmaf(-2.f, acc[mt * 4 + nt][reg], sj);
        int   ir = i0 + wi * 64 + mt * 16 + quad * 4 + reg;
        unsigned lr = (r < 8 ? (lip0 >> (r * 4)) : (lip1 >> ((r - 8) * 4))) & 0xFu;
        if ((unsigned)jl == lr) {
          if (j != ir && v > bpv[r]) { bpv[r] = v; bpi[r] = j; }
        } else {
          if (v < bnv[r]) { bnv[r] = v; bni[r] = j; }
        }
      }
    }
  }

  // reduce across the 16 l15-lanes of each quad
#pragma unroll
  for (int r = 0; r < 16; ++r) {
    float pvv = bpv[r]; int pii = bpi[r];
    float nvv = bnv[r]; int nii = bni[r];
#pragma unroll
    for (int m = 1; m < 16; m <<= 1) {
      float o  = __shfl_xor(pvv, m); int oi  = __shfl_xor(pii, m);
      if (o > pvv) { pvv = o; pii = oi; }
      float o2 = __shfl_xor(nvv, m); int oi2 = __shfl_xor(nii, m);
      if (o2 < nvv) { nvv = o2; nii = oi2; }
    }
    if (l15 == 0) {
      int ir = i0 + wi * 64 + (r >> 2) * 16 + quad * 4 + (r & 3);
      size_t idx = (size_t)(blockIdx.y * 2 + wj) * B_N + ir;
      pv[idx] = pvv; pi[idx] = pii;
      nv[idx] = nvv; ni[idx] = nii;
    }
  }
}

// ---- reduce partials + exact fp32 triplet distances + loss (+final divide) ----
__global__ void k_finish(const float* __restrict__ x,
                         const float* __restrict__ pv, const int* __restrict__ pi,
                         const float* __restrict__ nv, const int* __restrict__ ni,
                         float* __restrict__ sum, int* __restrict__ cnt,
                         int* __restrict__ done, float* __restrict__ out) {
  __shared__ float ssum[4];
  __shared__ int   scnt[4];
  int w = threadIdx.x >> 6, lane = threadIdx.x & 63;
  float lsum = 0.f; int lcnt = 0;
  for (int it = 0; it < 32; ++it) {
    int a = (blockIdx.x * 4 + w) * 32 + it;
    float bpvv = -1e30f; int bpii = -1;
    float bnvv = 1e30f;  int bnii = -1;
    if (lane < NP) {
      size_t idx = (size_t)lane * B_N + a;
      float v = pv[idx]; int ix = pi[idx];
      if (ix >= 0) { bpvv = v; bpii = ix; }
      float u = nv[idx]; int jx = ni[idx];
      if (jx >= 0) { bnvv = u; bnii = jx; }
    }
#pragma unroll
    for (int m = 1; m < 16; m <<= 1) {
      float o  = __shfl_xor(bpvv, m); int oi  = __shfl_xor(bpii, m);
      if (o > bpvv) { bpvv = o; bpii = oi; }
      float o2 = __shfl_xor(bnvv, m); int oi2 = __shfl_xor(bnii, m);
      if (o2 < bnvv) { bnvv = o2; bnii = oi2; }
    }
    bpii = __shfl(bpii, 0); bnii = __shfl(bnii, 0);
    bool valid = (bpii >= 0) && (bnii >= 0);
    int  pidx = valid ? bpii : 0;
    int  nidx = valid ? bnii : 0;

    float4 xa = *reinterpret_cast<const float4*>(x + (size_t)a * D_K + lane * 4);
    float4 xp = *reinterpret_cast<const float4*>(x + (size_t)pidx * D_K + lane * 4);
    float4 xn = *reinterpret_cast<const float4*>(x + (size_t)nidx * D_K + lane * 4);
    float dx, sp = 0.f, sn = 0.f;
    dx = xa.x - xp.x + 1e-6f; sp = fmaf(dx, dx, sp);
    dx = xa.y - xp.y + 1e-6f; sp = fmaf(dx, dx, sp);
    dx = xa.z - xp.z + 1e-6f; sp = fmaf(dx, dx, sp);
    dx = xa.w - xp.w + 1e-6f; sp = fmaf(dx, dx, sp);
    dx = xa.x - xn.x + 1e-6f; sn = fmaf(dx, dx, sn);
    dx = xa.y - xn.y + 1e-6f; sn = fmaf(dx, dx, sn);
    dx = xa.z - xn.z + 1e-6f; sn = fmaf(dx, dx, sn);
    dx = xa.w - xn.w + 1e-6f; sn = fmaf(dx, dx, sn);
#pragma unroll
    for (int o = 32; o > 0; o >>= 1) {
      sp += __shfl_down(sp, o, 64);
      sn += __shfl_down(sn, o, 64);
    }
    if (lane == 0 && valid) {
      float per = sqrtf(sp) - sqrtf(sn) + 0.3f;
      if (per > 0.f) lsum += per;
      lcnt += 1;
    }
  }
  if (lane == 0) { ssum[w] = lsum; scnt[w] = lcnt; }
  __syncthreads();
  if (threadIdx.x == 0) {
    atomicAdd(sum, ssum[0] + ssum[1] + ssum[2] + ssum[3]);
    atomicAdd(cnt, scnt[0] + scnt[1] + scnt[2] + scnt[3]);
    __threadfence();
    int prev = atomicAdd(done, 1);
    if (prev == gridDim.x - 1) {   // last block: publish the loss
      float s = atomicAdd(sum, 0.f);
      int   c = atomicAdd(cnt, 0);
      if (c < 1) c = 1;
      out[0] = s / (float)c;
    }
  }
}

extern "C" void kernel_launch(void* const* d_in, const int* in_sizes, int n_in,
                              void* d_out, int out_size, void* d_ws, size_t ws_size,
                              hipStream_t stream) {
  const float* x   = (const float*)d_in[0];
  const int*   lab = (const int*)d_in[1];
  float*       out = (float*)d_out;

  char* ws = (char*)d_ws;
  unsigned short* xhf = (unsigned short*)ws;                     // 4 MB
  float* sq = (float*)(ws + (size_t)4 * 1024 * 1024);            // 32 KB
  char*  pb = ws + (size_t)4 * 1024 * 1024 + 65536;
  size_t seg = (size_t)NP * B_N * 4;                             // 512 KB each
  float* pv  = (float*)(pb + 0 * seg);
  int*   pi  = (int*)(pb + 1 * seg);
  float* nv  = (float*)(pb + 2 * seg);
  int*   ni  = (int*)(pb + 3 * seg);
  float* sum = (float*)(pb + 4 * seg);
  int*   cnt = (int*)(sum + 1);
  int*   done = (int*)(sum + 2);

  k_split<<<B_N / 16, 256, 0, stream>>>(x, xhf, sq, sum, cnt, done);
  dim3 g(B_N / 128, NJ);
  k_mine3<<<g, 256, 0, stream>>>(xhf, lab, sq, pv, pi, nv, ni);
  k_finish<<<64, 256, 0, stream>>>(x, pv, pi, nv, ni, sum, cnt, done, out);
}

// Round 4
// 229.918 us; speedup vs baseline: 1.6250x; 1.6250x over previous
//
#include <hip/hip_runtime.h>
#include <math.h>

// EnhancedTripletLoss, B=8192, D=256, 8 classes.
// R4: A-tile in LDS (staged once, barrier-free hot loop), B streamed
// global->register from fragment-major bf16 buffer, single plane.
// Selection on v = sq_j - 2*dot (monotone per anchor); exact fp32 recompute
// of mined triplet distances (F.pairwise_distance eps semantics).

typedef __attribute__((ext_vector_type(8))) short short8;
typedef __attribute__((ext_vector_type(4))) float floatx4;

#define B_N 8192
#define D_K 256
#define NP  16

__device__ __forceinline__ unsigned short f2bf_rne(float f) {
  unsigned u = __float_as_uint(f);
  u += 0x7FFFu + ((u >> 16) & 1u);
  return (unsigned short)(u >> 16);
}

// ---- split to bf16 fragment-major + row norms + zero accumulators ----
// Tile (16 rows x 32 k) = 512 ushorts at [tile_row][tk][lane*8+j]:
// lane = quad*16 + m, row = 16*tile_row + m, k = 32*tk + quad*8 + j.
__global__ void k_split(const float* __restrict__ x, unsigned short* __restrict__ xhf,
                        float* __restrict__ sq, float* __restrict__ sum,
                        int* __restrict__ cnt, int* __restrict__ done) {
  __shared__ float sw[64];
  const int tid  = threadIdx.x;
  const int lane = tid & 63;
  const int w    = tid >> 6;
  const int b    = blockIdx.x;        // tile_row
  const int m    = lane & 15;
  const int quad = lane >> 4;
  const int row  = b * 16 + m;

  float s = 0.f;
#pragma unroll
  for (int h = 0; h < 2; ++h) {
    int tk = w + h * 4;
    int kk = tk * 32 + quad * 8;
    float4 f0 = *reinterpret_cast<const float4*>(x + (size_t)row * D_K + kk);
    float4 f1 = *reinterpret_cast<const float4*>(x + (size_t)row * D_K + kk + 4);
    s += f0.x * f0.x + f0.y * f0.y + f0.z * f0.z + f0.w * f0.w;
    s += f1.x * f1.x + f1.y * f1.y + f1.z * f1.z + f1.w * f1.w;
    ushort4 lo, hi;
    lo.x = f2bf_rne(f0.x); lo.y = f2bf_rne(f0.y); lo.z = f2bf_rne(f0.z); lo.w = f2bf_rne(f0.w);
    hi.x = f2bf_rne(f1.x); hi.y = f2bf_rne(f1.y); hi.z = f2bf_rne(f1.z); hi.w = f2bf_rne(f1.w);
    size_t o = ((size_t)b * 8 + tk) * 512 + lane * 8;
    *reinterpret_cast<ushort4*>(xhf + o)     = lo;
    *reinterpret_cast<ushort4*>(xhf + o + 4) = hi;
  }
  s += __shfl_xor(s, 16);
  s += __shfl_xor(s, 32);
  if (quad == 0) sw[w * 16 + m] = s;
  __syncthreads();
  if (tid < 16) sq[b * 16 + tid] = sw[tid] + sw[16 + tid] + sw[32 + tid] + sw[48 + tid];
  if (b == 0 && tid == 0) { *sum = 0.f; *cnt = 0; *done = 0; }
}

// ---- MFMA Gram + hard mining: A in LDS, B global->reg, no hot-loop barriers ----
__global__ __launch_bounds__(256, 2) void k_mine4(
    const unsigned short* __restrict__ xhf, const int* __restrict__ lab,
    const float* __restrict__ sq,
    float* __restrict__ pv, int* __restrict__ pi,
    float* __restrict__ nv, int* __restrict__ ni) {
  __shared__ unsigned short Alds[8 * 8 * 512];   // 64 KB: [mtile 8][tk 8][512]

  const int tid  = threadIdx.x;
  const int lane = tid & 63;
  const int w    = tid >> 6;
  const int wi   = w >> 1, wj = w & 1;
  const int quad = lane >> 4, l15 = lane & 15;
  const int i0   = blockIdx.x * 128;
  const int by   = blockIdx.y;

  // stage A: one contiguous 64 KB copy (fragment-major already)
  {
    const short8* src = reinterpret_cast<const short8*>(xhf + (size_t)blockIdx.x * 32768);
    short8* dst = reinterpret_cast<short8*>(Alds);
#pragma unroll
    for (int it = 0; it < 16; ++it) dst[it * 256 + tid] = src[it * 256 + tid];
  }

  float bpv[16], bnv[16];
  int   bpi[16], bni[16];
  unsigned lip0 = 0, lip1 = 0;
#pragma unroll
  for (int r = 0; r < 16; ++r) {
    bpv[r] = -1e30f; bnv[r] = 1e30f; bpi[r] = -1; bni[r] = -1;
    int ir = i0 + wi * 64 + (r >> 2) * 16 + quad * 4 + (r & 3);
    unsigned lv = (unsigned)lab[ir] & 0xFu;
    if (r < 8) lip0 |= lv << (r * 4); else lip1 |= lv << ((r - 8) * 4);
  }
  __syncthreads();   // the only barrier

  // B pointer at (tile_row = by*64 + wj*4, tk) advancing fragment-major
  const unsigned short* Bp = xhf + ((size_t)(by * 64 + wj * 4) * 8) * 512 + lane * 8;

  short8 Acur[4], Anxt[4], Bcur[4], Bnxt[4];
#pragma unroll
  for (int mt = 0; mt < 4; ++mt)
    Acur[mt] = *reinterpret_cast<const short8*>(Alds + ((wi * 4 + mt) * 8 + 0) * 512 + lane * 8);
#pragma unroll
  for (int nt = 0; nt < 4; ++nt)
    Bcur[nt] = *reinterpret_cast<const short8*>(Bp + nt * 4096);
  Bp += 512;   // now points at t=1

  for (int sub = 0; sub < 8; ++sub) {
    floatx4 acc[16];
#pragma unroll
    for (int q = 0; q < 16; ++q) acc[q] = (floatx4)0.f;

#pragma unroll
    for (int tk = 0; tk < 8; ++tk) {
      // prefetch t+1 (last iteration reads slack garbage; never consumed)
      const int ntk = (tk + 1) & 7;
#pragma unroll
      for (int nt = 0; nt < 4; ++nt)
        Bnxt[nt] = *reinterpret_cast<const short8*>(Bp + nt * 4096);
#pragma unroll
      for (int mt = 0; mt < 4; ++mt)
        Anxt[mt] = *reinterpret_cast<const short8*>(Alds + ((wi * 4 + mt) * 8 + ntk) * 512 + lane * 8);

#pragma unroll
      for (int mt = 0; mt < 4; ++mt)
#pragma unroll
        for (int nt = 0; nt < 4; ++nt)
          acc[mt * 4 + nt] = __builtin_amdgcn_mfma_f32_16x16x32_bf16(
              Acur[mt], Bcur[nt], acc[mt * 4 + nt], 0, 0, 0);

#pragma unroll
      for (int q = 0; q < 4; ++q) { Acur[q] = Anxt[q]; Bcur[q] = Bnxt[q]; }
      Bp += (tk == 6) ? 29184 : 512;   // wrap to next subtile after t+1 crosses
    }

    // selection on v = sq_j - 2*dot; self never wins argmax-pos (d^2=0) so no
    // j!=i check needed; self is same-label so excluded from neg by eq.
    const int j0 = by * 1024 + sub * 128;
#pragma unroll
    for (int nt = 0; nt < 4; ++nt) {
      int   j  = j0 + wj * 64 + nt * 16 + l15;
      int   jl = lab[j];
      float sj = sq[j];
#pragma unroll
      for (int r = 0; r < 16; ++r) {
        int mt = r >> 2, reg = r & 3;
        float v = fmaf(-2.f, acc[mt * 4 + nt][reg], sj);
        unsigned lr = (r < 8 ? (lip0 >> (r * 4)) : (lip1 >> ((r - 8) * 4))) & 0xFu;
        bool eq = ((unsigned)jl == lr);
        bool pu = eq && (v > bpv[r]);
        bpv[r] = pu ? v : bpv[r];
        bpi[r] = pu ? j : bpi[r];
        bool nu = (!eq) && (v < bnv[r]);
        bnv[r] = nu ? v : bnv[r];
        bni[r] = nu ? j : bni[r];
      }
    }
  }

  // reduce across the 16 l15-lanes of each quad
#pragma unroll
  for (int r = 0; r < 16; ++r) {
    float pvv = bpv[r]; int pii = bpi[r];
    float nvv = bnv[r]; int nii = bni[r];
#pragma unroll
    for (int m = 1; m < 16; m <<= 1) {
      float o  = __shfl_xor(pvv, m); int oi  = __shfl_xor(pii, m);
      if (o > pvv) { pvv = o; pii = oi; }
      float o2 = __shfl_xor(nvv, m); int oi2 = __shfl_xor(nii, m);
      if (o2 < nvv) { nvv = o2; nii = oi2; }
    }
    if (l15 == 0) {
      int ir = i0 + wi * 64 + (r >> 2) * 16 + quad * 4 + (r & 3);
      size_t idx = (size_t)(by * 2 + wj) * B_N + ir;
      pv[idx] = pvv; pi[idx] = pii;
      nv[idx] = nvv; ni[idx] = nii;
    }
  }
}

// ---- reduce partials + exact fp32 triplet distances + loss + final divide ----
__global__ void k_finish(const float* __restrict__ x,
                         const float* __restrict__ pv, const int* __restrict__ pi,
                         const float* __restrict__ nv, const int* __restrict__ ni,
                         float* __restrict__ sum, int* __restrict__ cnt,
                         int* __restrict__ done, float* __restrict__ out) {
  __shared__ float ssum[4];
  __shared__ int   scnt[4];
  int w = threadIdx.x >> 6, lane = threadIdx.x & 63;
  float lsum = 0.f; int lcnt = 0;
  for (int it = 0; it < 32; ++it) {
    int a = (blockIdx.x * 4 + w) * 32 + it;
    float bpvv = -1e30f; int bpii = -1;
    float bnvv = 1e30f;  int bnii = -1;
    if (lane < NP) {
      size_t idx = (size_t)lane * B_N + a;
      float v = pv[idx]; int ix = pi[idx];
      if (ix >= 0) { bpvv = v; bpii = ix; }
      float u = nv[idx]; int jx = ni[idx];
      if (jx >= 0) { bnvv = u; bnii = jx; }
    }
#pragma unroll
    for (int m = 1; m < 16; m <<= 1) {
      float o  = __shfl_xor(bpvv, m); int oi  = __shfl_xor(bpii, m);
      if (o > bpvv) { bpvv = o; bpii = oi; }
      float o2 = __shfl_xor(bnvv, m); int oi2 = __shfl_xor(bnii, m);
      if (o2 < bnvv) { bnvv = o2; bnii = oi2; }
    }
    bpii = __shfl(bpii, 0); bnii = __shfl(bnii, 0);
    bool valid = (bpii >= 0) && (bnii >= 0);
    int  pidx = valid ? bpii : 0;
    int  nidx = valid ? bnii : 0;

    float4 xa = *reinterpret_cast<const float4*>(x + (size_t)a * D_K + lane * 4);
    float4 xp = *reinterpret_cast<const float4*>(x + (size_t)pidx * D_K + lane * 4);
    float4 xn = *reinterpret_cast<const float4*>(x + (size_t)nidx * D_K + lane * 4);
    float dx, sp = 0.f, sn = 0.f;
    dx = xa.x - xp.x + 1e-6f; sp = fmaf(dx, dx, sp);
    dx = xa.y - xp.y + 1e-6f; sp = fmaf(dx, dx, sp);
    dx = xa.z - xp.z + 1e-6f; sp = fmaf(dx, dx, sp);
    dx = xa.w - xp.w + 1e-6f; sp = fmaf(dx, dx, sp);
    dx = xa.x - xn.x + 1e-6f; sn = fmaf(dx, dx, sn);
    dx = xa.y - xn.y + 1e-6f; sn = fmaf(dx, dx, sn);
    dx = xa.z - xn.z + 1e-6f; sn = fmaf(dx, dx, sn);
    dx = xa.w - xn.w + 1e-6f; sn = fmaf(dx, dx, sn);
#pragma unroll
    for (int o = 32; o > 0; o >>= 1) {
      sp += __shfl_down(sp, o, 64);
      sn += __shfl_down(sn, o, 64);
    }
    if (lane == 0 && valid) {
      float per = sqrtf(sp) - sqrtf(sn) + 0.3f;
      if (per > 0.f) lsum += per;
      lcnt += 1;
    }
  }
  if (lane == 0) { ssum[w] = lsum; scnt[w] = lcnt; }
  __syncthreads();
  if (threadIdx.x == 0) {
    atomicAdd(sum, ssum[0] + ssum[1] + ssum[2] + ssum[3]);
    atomicAdd(cnt, scnt[0] + scnt[1] + scnt[2] + scnt[3]);
    __threadfence();
    int prev = atomicAdd(done, 1);
    if (prev == gridDim.x - 1) {
      float s = atomicAdd(sum, 0.f);
      int   c = atomicAdd(cnt, 0);
      if (c < 1) c = 1;
      out[0] = s / (float)c;
    }
  }
}

extern "C" void kernel_launch(void* const* d_in, const int* in_sizes, int n_in,
                              void* d_out, int out_size, void* d_ws, size_t ws_size,
                              hipStream_t stream) {
  const float* x   = (const float*)d_in[0];
  const int*   lab = (const int*)d_in[1];
  float*       out = (float*)d_out;

  char* ws = (char*)d_ws;
  unsigned short* xhf = (unsigned short*)ws;                      // 4 MB + 512 KB slack
  float* sq = (float*)(ws + (size_t)4608 * 1024);                 // 32 KB
  char*  pb = ws + (size_t)4608 * 1024 + 65536;
  size_t seg = (size_t)NP * B_N * 4;                              // 512 KB each
  float* pv   = (float*)(pb + 0 * seg);
  int*   pi   = (int*)(pb + 1 * seg);
  float* nv   = (float*)(pb + 2 * seg);
  int*   ni   = (int*)(pb + 3 * seg);
  float* sum  = (float*)(pb + 4 * seg);
  int*   cnt  = (int*)(sum + 1);
  int*   done = (int*)(sum + 2);

  k_split<<<B_N / 16, 256, 0, stream>>>(x, xhf, sq, sum, cnt, done);
  dim3 g(B_N / 128, 8);
  k_mine4<<<g, 256, 0, stream>>>(xhf, lab, sq, pv, pi, nv, ni);
  k_finish<<<64, 256, 0, stream>>>(x, pv, pi, nv, ni, sum, cnt, done, out);
}

// Round 5
// 161.668 us; speedup vs baseline: 2.3110x; 1.4222x over previous
//
#include <hip/hip_runtime.h>
#include <math.h>

// EnhancedTripletLoss, B=8192, D=256, 8 classes.
// R5: A-tile in LDS (staged once, 1 barrier), B streamed global->reg from
// fragment-major bf16, packed u32 selection keys ((q19(v)<<13)|j) to halve
// selection registers and partial traffic. Exact fp32 recompute of mined
// triplet distances (F.pairwise_distance eps semantics).

typedef __attribute__((ext_vector_type(8))) short short8;
typedef __attribute__((ext_vector_type(4))) float floatx4;

#define B_N 8192
#define D_K 256
#define NP  16

__device__ __forceinline__ unsigned short f2bf_rne(float f) {
  unsigned u = __float_as_uint(f);
  u += 0x7FFFu + ((u >> 16) & 1u);
  return (unsigned short)(u >> 16);
}

// ---- split to bf16 fragment-major + row norms + zero accumulators ----
// Tile (16 rows x 32 k) = 512 ushorts at [tile_row][tk][lane*8+j]:
// lane = quad*16 + m, row = 16*tile_row + m, k = 32*tk + quad*8 + j.
__global__ void k_split(const float* __restrict__ x, unsigned short* __restrict__ xhf,
                        float* __restrict__ sq, float* __restrict__ sum,
                        int* __restrict__ cnt, int* __restrict__ done) {
  __shared__ float sw[64];
  const int tid  = threadIdx.x;
  const int lane = tid & 63;
  const int w    = tid >> 6;
  const int b    = blockIdx.x;        // tile_row
  const int m    = lane & 15;
  const int quad = lane >> 4;
  const int row  = b * 16 + m;

  float s = 0.f;
#pragma unroll
  for (int h = 0; h < 2; ++h) {
    int tk = w + h * 4;
    int kk = tk * 32 + quad * 8;
    float4 f0 = *reinterpret_cast<const float4*>(x + (size_t)row * D_K + kk);
    float4 f1 = *reinterpret_cast<const float4*>(x + (size_t)row * D_K + kk + 4);
    s += f0.x * f0.x + f0.y * f0.y + f0.z * f0.z + f0.w * f0.w;
    s += f1.x * f1.x + f1.y * f1.y + f1.z * f1.z + f1.w * f1.w;
    ushort4 lo, hi;
    lo.x = f2bf_rne(f0.x); lo.y = f2bf_rne(f0.y); lo.z = f2bf_rne(f0.z); lo.w = f2bf_rne(f0.w);
    hi.x = f2bf_rne(f1.x); hi.y = f2bf_rne(f1.y); hi.z = f2bf_rne(f1.z); hi.w = f2bf_rne(f1.w);
    size_t o = ((size_t)b * 8 + tk) * 512 + lane * 8;
    *reinterpret_cast<ushort4*>(xhf + o)     = lo;
    *reinterpret_cast<ushort4*>(xhf + o + 4) = hi;
  }
  s += __shfl_xor(s, 16);
  s += __shfl_xor(s, 32);
  if (quad == 0) sw[w * 16 + m] = s;
  __syncthreads();
  if (tid < 16) sq[b * 16 + tid] = sw[tid] + sw[16 + tid] + sw[32 + tid] + sw[48 + tid];
  if (b == 0 && tid == 0) { *sum = 0.f; *cnt = 0; *done = 0; }
}

// ---- MFMA Gram + hard mining: A in LDS, B global->reg, packed-key select ----
__global__ __launch_bounds__(256, 2) void k_mine5(
    const unsigned short* __restrict__ xhf, const int* __restrict__ lab,
    const float* __restrict__ sq,
    unsigned* __restrict__ pk, unsigned* __restrict__ nk) {
  __shared__ unsigned short Alds[8 * 8 * 512];   // 64 KB: [mtile 8][tk 8][512]

  const int tid  = threadIdx.x;
  const int lane = tid & 63;
  const int w    = tid >> 6;
  const int wi   = w >> 1, wj = w & 1;
  const int quad = lane >> 4, l15 = lane & 15;
  const int i0   = blockIdx.x * 128;
  const int by   = blockIdx.y;

  // stage A: one contiguous 64 KB copy (fragment-major already)
  {
    const short8* src = reinterpret_cast<const short8*>(xhf + (size_t)blockIdx.x * 32768);
    short8* dst = reinterpret_cast<short8*>(Alds);
#pragma unroll
    for (int it = 0; it < 16; ++it) dst[it * 256 + tid] = src[it * 256 + tid];
  }

  unsigned pkey[16], nkey[16];
  unsigned lip0 = 0, lip1 = 0;
#pragma unroll
  for (int r = 0; r < 16; ++r) {
    pkey[r] = 0u; nkey[r] = 0xFFFFFFFFu;
    int ir = i0 + wi * 64 + (r >> 2) * 16 + quad * 4 + (r & 3);
    unsigned lv = (unsigned)lab[ir] & 0xFu;
    if (r < 8) lip0 |= lv << (r * 4); else lip1 |= lv << ((r - 8) * 4);
  }
  __syncthreads();   // the only barrier

  // B frag base for this wave: tile_row = by*64 + wj*4 (+ sub*8 + nt)
  const unsigned short* Bw = xhf + ((size_t)(by * 64 + wj * 4) * 8) * 512 + lane * 8;
  const unsigned short* Aw = Alds + (size_t)wi * 32 * 512 + lane * 8;

  for (int sub = 0; sub < 8; ++sub) {
    floatx4 acc[16];
#pragma unroll
    for (int q = 0; q < 16; ++q) acc[q] = (floatx4)0.f;

#pragma unroll
    for (int tk = 0; tk < 8; ++tk) {
      short8 Bf[4];
#pragma unroll
      for (int nt = 0; nt < 4; ++nt)
        Bf[nt] = *reinterpret_cast<const short8*>(Bw + (size_t)sub * 32768 + nt * 4096 + tk * 512);
#pragma unroll
      for (int mt = 0; mt < 4; ++mt) {
        short8 Af = *reinterpret_cast<const short8*>(Aw + (size_t)(mt * 8 + tk) * 512);
#pragma unroll
        for (int nt = 0; nt < 4; ++nt)
          acc[mt * 4 + nt] = __builtin_amdgcn_mfma_f32_16x16x32_bf16(
              Af, Bf[nt], acc[mt * 4 + nt], 0, 0, 0);
      }
    }

    // selection on v = sq_j - 2*dot (monotone in distance per anchor).
    // key = (quant19(v) << 13) | j ; pos: umax, neg: umin. Self never wins
    // argmax-pos (its v = -sq_i is the per-row minimum).
    const int j0 = by * 1024 + sub * 128;
#pragma unroll
    for (int nt = 0; nt < 4; ++nt) {
      int      j  = j0 + wj * 64 + nt * 16 + l15;
      unsigned jl = (unsigned)lab[j] & 0xFu;
      float    sj = sq[j];
#pragma unroll
      for (int r = 0; r < 16; ++r) {
        int mt = r >> 2, reg = r & 3;
        float v = fmaf(-2.f, acc[mt * 4 + nt][reg], sj);
        unsigned kq  = (unsigned)fmaf(v, 128.f, 262144.f);   // v in (-2048,2048)
        unsigned key = (kq << 13) | (unsigned)j;
        unsigned lr  = (r < 8 ? (lip0 >> (r * 4)) : (lip1 >> ((r - 8) * 4))) & 0xFu;
        bool eq = (jl == lr);
        unsigned pc = eq ? key : 0u;
        unsigned nc = eq ? 0xFFFFFFFFu : key;
        pkey[r] = pkey[r] > pc ? pkey[r] : pc;
        nkey[r] = nkey[r] < nc ? nkey[r] : nc;
      }
    }
  }

  // reduce across the 16 l15-lanes of each quad
#pragma unroll
  for (int r = 0; r < 16; ++r) {
    unsigned p = pkey[r], n = nkey[r];
#pragma unroll
    for (int m = 1; m < 16; m <<= 1) {
      unsigned op = (unsigned)__shfl_xor((int)p, m);
      unsigned on = (unsigned)__shfl_xor((int)n, m);
      p = p > op ? p : op;
      n = n < on ? n : on;
    }
    if (l15 == 0) {
      int ir = i0 + wi * 64 + (r >> 2) * 16 + quad * 4 + (r & 3);
      size_t idx = (size_t)(by * 2 + wj) * B_N + ir;
      pk[idx] = p;
      nk[idx] = n;
    }
  }
}

// ---- reduce partials + exact fp32 triplet distances + loss + final divide ----
__global__ void k_finish(const float* __restrict__ x,
                         const unsigned* __restrict__ pk, const unsigned* __restrict__ nk,
                         float* __restrict__ sum, int* __restrict__ cnt,
                         int* __restrict__ done, float* __restrict__ out) {
  __shared__ float ssum[4];
  __shared__ int   scnt[4];
  int w = threadIdx.x >> 6, lane = threadIdx.x & 63;
  float lsum = 0.f; int lcnt = 0;
  for (int it = 0; it < 8; ++it) {
    int a = (blockIdx.x * 4 + w) * 8 + it;
    unsigned p = 0u, n = 0xFFFFFFFFu;
    if (lane < NP) {
      p = pk[(size_t)lane * B_N + a];
      n = nk[(size_t)lane * B_N + a];
    }
#pragma unroll
    for (int m = 1; m < 16; m <<= 1) {
      unsigned op = (unsigned)__shfl_xor((int)p, m);
      unsigned on = (unsigned)__shfl_xor((int)n, m);
      p = p > op ? p : op;
      n = n < on ? n : on;
    }
    p = (unsigned)__shfl((int)p, 0);
    n = (unsigned)__shfl((int)n, 0);
    bool valid = (p != 0u) && (n != 0xFFFFFFFFu);
    int  pidx = valid ? (int)(p & 8191u) : 0;
    int  nidx = valid ? (int)(n & 8191u) : 0;

    float4 xa = *reinterpret_cast<const float4*>(x + (size_t)a * D_K + lane * 4);
    float4 xp = *reinterpret_cast<const float4*>(x + (size_t)pidx * D_K + lane * 4);
    float4 xn = *reinterpret_cast<const float4*>(x + (size_t)nidx * D_K + lane * 4);
    float dx, sp = 0.f, sn = 0.f;
    dx = xa.x - xp.x + 1e-6f; sp = fmaf(dx, dx, sp);
    dx = xa.y - xp.y + 1e-6f; sp = fmaf(dx, dx, sp);
    dx = xa.z - xp.z + 1e-6f; sp = fmaf(dx, dx, sp);
    dx = xa.w - xp.w + 1e-6f; sp = fmaf(dx, dx, sp);
    dx = xa.x - xn.x + 1e-6f; sn = fmaf(dx, dx, sn);
    dx = xa.y - xn.y + 1e-6f; sn = fmaf(dx, dx, sn);
    dx = xa.z - xn.z + 1e-6f; sn = fmaf(dx, dx, sn);
    dx = xa.w - xn.w + 1e-6f; sn = fmaf(dx, dx, sn);
#pragma unroll
    for (int o = 32; o > 0; o >>= 1) {
      sp += __shfl_down(sp, o, 64);
      sn += __shfl_down(sn, o, 64);
    }
    if (lane == 0 && valid) {
      float per = sqrtf(sp) - sqrtf(sn) + 0.3f;
      if (per > 0.f) lsum += per;
      lcnt += 1;
    }
  }
  if (lane == 0) { ssum[w] = lsum; scnt[w] = lcnt; }
  __syncthreads();
  if (threadIdx.x == 0) {
    atomicAdd(sum, ssum[0] + ssum[1] + ssum[2] + ssum[3]);
    atomicAdd(cnt, scnt[0] + scnt[1] + scnt[2] + scnt[3]);
    __threadfence();
    int prev = atomicAdd(done, 1);
    if (prev == gridDim.x - 1) {
      float s = atomicAdd(sum, 0.f);
      int   c = atomicAdd(cnt, 0);
      if (c < 1) c = 1;
      out[0] = s / (float)c;
    }
  }
}

extern "C" void kernel_launch(void* const* d_in, const int* in_sizes, int n_in,
                              void* d_out, int out_size, void* d_ws, size_t ws_size,
                              hipStream_t stream) {
  const float* x   = (const float*)d_in[0];
  const int*   lab = (const int*)d_in[1];
  float*       out = (float*)d_out;

  char* ws = (char*)d_ws;
  unsigned short* xhf = (unsigned short*)ws;                      // 4 MB
  float* sq = (float*)(ws + (size_t)4608 * 1024);                 // 32 KB
  char*  pb = ws + (size_t)4608 * 1024 + 65536;
  size_t seg = (size_t)NP * B_N * 4;                              // 512 KB each
  unsigned* pk  = (unsigned*)(pb + 0 * seg);
  unsigned* nk  = (unsigned*)(pb + 1 * seg);
  float* sum  = (float*)(pb + 2 * seg);
  int*   cnt  = (int*)(sum + 1);
  int*   done = (int*)(sum + 2);

  k_split<<<B_N / 16, 256, 0, stream>>>(x, xhf, sq, sum, cnt, done);
  dim3 g(B_N / 128, 8);
  k_mine5<<<g, 256, 0, stream>>>(xhf, lab, sq, pk, nk);
  k_finish<<<256, 256, 0, stream>>>(x, pk, nk, sum, cnt, done, out);
}